// Round 6
// baseline (16437.025 us; speedup 1.0000x reference)
//
#include <hip/hip_runtime.h>

#define NB    1024
#define TSEQ  336
#define DIM   64
#define GATES 256
#define PRED  96

// ============================ SPLIT-PHASE KERNEL =============================
// 1024 threads. Phases per block (4 batch rows each, no cross-block deps):
//   phase1: layer-0 over 336 steps, Wih0+Whh0 resident (32 floats/lane),
//           h0 -> LDS (next step) + h0buf (workspace, for phase 2)
//   phase2: layer-1 over 336 steps, Wih1+Whh1 resident (32 floats/lane),
//           ih input = h0buf (global, wave-uniform), h1 kept in LDS
//   phase3: decoder 96 steps, Wih0 (lanes 0-511) / Wih1 (lanes 512-1023),
//           zero-state cells, FC from LDS
// RATIONALE (R2-R5): 1024-thr blocks have a hard 64-VGPR RA budget on this
// toolchain; 64-float weight residency spills to scratch (40 GB HBM). 32-float
// residency + ~25 working regs fits. Encoder uses the PROVEN non-pipelined
// 2-barrier pattern (pipelined variants failed twice: R1, R5).

// LDS layout (float offsets)
#define PO    0      // partials [4 copies][4 rows][256 gates]
#define WFCO  4096   // W_fc [16][4][64] : (k4,c,j) = W[j][4k4+c]
#define H0O   8192   // [4][64]
#define H1O   8448   // [4][64]
#define DBO   8704   // [4][64] decoder feedback
#define BS0O  8960   // 256
#define BS1O  9216   // 256
#define BFCO  9472   // 64
#define SMF   9536
#define SMEM_BYTES (SMF * 4)

__device__ __forceinline__ float sigm(float v)  { return 1.0f / (1.0f + __expf(-v)); }
__device__ __forceinline__ float tanh_(float v) { return 1.0f - 2.0f / (__expf(2.0f * v) + 1.0f); }

__device__ __forceinline__ void fma4v(float& acc, const float4 xv, const float4 w) {
    acc = fmaf(xv.x, w.x, acc); acc = fmaf(xv.y, w.y, acc);
    acc = fmaf(xv.z, w.z, acc); acc = fmaf(xv.w, w.w, acc);
}

extern "C" __global__ void __launch_bounds__(1024)
rnn_split(const float* __restrict__ x,
          const float* __restrict__ Wih0, const float* __restrict__ Whh0,
          const float* __restrict__ bih0, const float* __restrict__ bhh0,
          const float* __restrict__ Wih1, const float* __restrict__ Whh1,
          const float* __restrict__ bih1, const float* __restrict__ bhh1,
          const float* __restrict__ Wfc,  const float* __restrict__ bfc,
          float* __restrict__ out, float* __restrict__ h0buf)
{
    extern __shared__ float sm[];
    const int tid = threadIdx.x;
    const int bid = blockIdx.x;
    const int sub = tid >> 8;          // 0..3 (wave-uniform)
    const int mm  = sub >> 1;          // 0: ih matvec, 1: hh matvec
    const int kh  = sub & 1;           // k-half
    const int g0  = tid & 255;         // owned gate row
    const int rr  = (tid & 255) >> 6;  // combine row
    const int jj  = tid & 63;          // combine hidden index
    const int row0 = bid * 4;

    // ---- prologue staging ----
    if (tid < GATES) {
        sm[BS0O + tid] = bih0[tid] + bhh0[tid];
        sm[BS1O + tid] = bih1[tid] + bhh1[tid];
    }
    if (tid < DIM) sm[BFCO + tid] = bfc[tid];
    if (tid < 256) { sm[H0O + tid] = 0.0f; sm[H1O + tid] = 0.0f; }
    for (int idx = tid; idx < DIM * DIM; idx += 1024) {   // W_fc: (k4,c,j)
        const int j = idx >> 6, k = idx & 63;
        sm[WFCO + (k >> 2) * 256 + (k & 3) * 64 + j] = Wfc[idx];
    }

    // ================= phase 1: layer 0 (Wih0 + Whh0) =================
    {
        const float* Wsrc = mm ? Whh0 : Wih0;
        float4 w[8];
#pragma unroll
        for (int k4 = 0; k4 < 8; ++k4)
            w[k4] = *reinterpret_cast<const float4*>(Wsrc + g0 * DIM + kh * 32 + k4 * 4);
        __syncthreads();

        const float* xr0 = x + (size_t)(row0 + 0) * TSEQ * DIM + kh * 32;
        const float* xr1 = x + (size_t)(row0 + 1) * TSEQ * DIM + kh * 32;
        const float* xr2 = x + (size_t)(row0 + 2) * TSEQ * DIM + kh * 32;
        const float* xr3 = x + (size_t)(row0 + 3) * TSEQ * DIM + kh * 32;
        float c0 = 0.0f;

        for (int s = 0; s < TSEQ; ++s) {
            float acc[4] = {0.f, 0.f, 0.f, 0.f};
            if (mm == 0) {          // ih part: wave-uniform global x loads
                const int so = s * DIM;
#pragma unroll
                for (int k4 = 0; k4 < 8; ++k4) {
                    fma4v(acc[0], *reinterpret_cast<const float4*>(xr0 + so + k4 * 4), w[k4]);
                    fma4v(acc[1], *reinterpret_cast<const float4*>(xr1 + so + k4 * 4), w[k4]);
                    fma4v(acc[2], *reinterpret_cast<const float4*>(xr2 + so + k4 * 4), w[k4]);
                    fma4v(acc[3], *reinterpret_cast<const float4*>(xr3 + so + k4 * 4), w[k4]);
                }
            } else {                // hh part: wave-uniform LDS broadcasts
                const float* ib = sm + H0O + kh * 32;
#pragma unroll
                for (int k4 = 0; k4 < 8; ++k4) {
                    fma4v(acc[0], *reinterpret_cast<const float4*>(ib + 0 * 64 + k4 * 4), w[k4]);
                    fma4v(acc[1], *reinterpret_cast<const float4*>(ib + 1 * 64 + k4 * 4), w[k4]);
                    fma4v(acc[2], *reinterpret_cast<const float4*>(ib + 2 * 64 + k4 * 4), w[k4]);
                    fma4v(acc[3], *reinterpret_cast<const float4*>(ib + 3 * 64 + k4 * 4), w[k4]);
                }
            }
            float* dst = sm + PO + sub * 1024 + g0;
            dst[0] = acc[0]; dst[256] = acc[1]; dst[512] = acc[2]; dst[768] = acc[3];
            __syncthreads();

            if (tid < 256) {        // combine: 4 copies + bias
                float pi = sm[BS0O + jj],       pf = sm[BS0O + 64 + jj];
                float pg = sm[BS0O + 128 + jj], po = sm[BS0O + 192 + jj];
#pragma unroll
                for (int cp = 0; cp < 4; ++cp) {
                    const float* p = sm + PO + cp * 1024 + rr * 256;
                    pi += p[jj]; pf += p[64 + jj]; pg += p[128 + jj]; po += p[192 + jj];
                }
                const float ig = sigm(pi), fg = sigm(pf), gg = tanh_(pg), og = sigm(po);
                c0 = fmaf(fg, c0, ig * gg);
                const float h = og * tanh_(c0);
                sm[H0O + tid] = h;
                h0buf[(size_t)(row0 + rr) * TSEQ * DIM + s * DIM + jj] = h;
            }
            __syncthreads();
        }
    }

    // ================= phase 2: layer 1 (Wih1 + Whh1) =================
    {
        const float* Wsrc = mm ? Whh1 : Wih1;
        float4 w[8];
#pragma unroll
        for (int k4 = 0; k4 < 8; ++k4)
            w[k4] = *reinterpret_cast<const float4*>(Wsrc + g0 * DIM + kh * 32 + k4 * 4);

        const float* hr0 = h0buf + (size_t)(row0 + 0) * TSEQ * DIM + kh * 32;
        const float* hr1 = h0buf + (size_t)(row0 + 1) * TSEQ * DIM + kh * 32;
        const float* hr2 = h0buf + (size_t)(row0 + 2) * TSEQ * DIM + kh * 32;
        const float* hr3 = h0buf + (size_t)(row0 + 3) * TSEQ * DIM + kh * 32;
        float c1 = 0.0f;
        // H1O is still 0 from prologue (phase 1 never writes it).

        for (int s = 0; s < TSEQ; ++s) {
            float acc[4] = {0.f, 0.f, 0.f, 0.f};
            if (mm == 0) {          // ih part: wave-uniform global h0 loads (own writes, same CU/L2)
                const int so = s * DIM;
#pragma unroll
                for (int k4 = 0; k4 < 8; ++k4) {
                    fma4v(acc[0], *reinterpret_cast<const float4*>(hr0 + so + k4 * 4), w[k4]);
                    fma4v(acc[1], *reinterpret_cast<const float4*>(hr1 + so + k4 * 4), w[k4]);
                    fma4v(acc[2], *reinterpret_cast<const float4*>(hr2 + so + k4 * 4), w[k4]);
                    fma4v(acc[3], *reinterpret_cast<const float4*>(hr3 + so + k4 * 4), w[k4]);
                }
            } else {                // hh part: h1_{s-1} from LDS
                const float* ib = sm + H1O + kh * 32;
#pragma unroll
                for (int k4 = 0; k4 < 8; ++k4) {
                    fma4v(acc[0], *reinterpret_cast<const float4*>(ib + 0 * 64 + k4 * 4), w[k4]);
                    fma4v(acc[1], *reinterpret_cast<const float4*>(ib + 1 * 64 + k4 * 4), w[k4]);
                    fma4v(acc[2], *reinterpret_cast<const float4*>(ib + 2 * 64 + k4 * 4), w[k4]);
                    fma4v(acc[3], *reinterpret_cast<const float4*>(ib + 3 * 64 + k4 * 4), w[k4]);
                }
            }
            float* dst = sm + PO + sub * 1024 + g0;
            dst[0] = acc[0]; dst[256] = acc[1]; dst[512] = acc[2]; dst[768] = acc[3];
            __syncthreads();

            if (tid < 256) {
                float pi = sm[BS1O + jj],       pf = sm[BS1O + 64 + jj];
                float pg = sm[BS1O + 128 + jj], po = sm[BS1O + 192 + jj];
#pragma unroll
                for (int cp = 0; cp < 4; ++cp) {
                    const float* p = sm + PO + cp * 1024 + rr * 256;
                    pi += p[jj]; pf += p[64 + jj]; pg += p[128 + jj]; po += p[192 + jj];
                }
                const float ig = sigm(pi), fg = sigm(pf), gg = tanh_(pg), og = sigm(po);
                c1 = fmaf(fg, c1, ig * gg);
                sm[H1O + tid] = og * tanh_(c1);
            }
            __syncthreads();
        }
    }

    // ================= phase 3: decoder (96 zero-state steps) =================
    {
        const int dsub = tid >> 9;         // 0: Wih0 team (lanes 0-511), 1: Wih1 team
        const int dkh  = (tid >> 8) & 1;   // k-half within team
        const float* Wsrc = dsub ? Wih1 : Wih0;
        float4 w[8];
#pragma unroll
        for (int k4 = 0; k4 < 8; ++k4)
            w[k4] = *reinterpret_cast<const float4*>(Wsrc + g0 * DIM + dkh * 32 + k4 * 4);

        if (tid < 256) sm[DBO + tid] = sm[H1O + tid];   // db = h1_last
        __syncthreads();
        const float bfc_j = sm[BFCO + jj];

        for (int p = 0; p < PRED; ++p) {
            if (dsub == 0) {      // cell0 partials: Wih0 . db -> copies 0,1
                float acc[4] = {0.f, 0.f, 0.f, 0.f};
                const float* ib = sm + DBO + dkh * 32;
#pragma unroll
                for (int k4 = 0; k4 < 8; ++k4) {
                    fma4v(acc[0], *reinterpret_cast<const float4*>(ib + 0 * 64 + k4 * 4), w[k4]);
                    fma4v(acc[1], *reinterpret_cast<const float4*>(ib + 1 * 64 + k4 * 4), w[k4]);
                    fma4v(acc[2], *reinterpret_cast<const float4*>(ib + 2 * 64 + k4 * 4), w[k4]);
                    fma4v(acc[3], *reinterpret_cast<const float4*>(ib + 3 * 64 + k4 * 4), w[k4]);
                }
                float* dst = sm + PO + dkh * 1024 + g0;
                dst[0] = acc[0]; dst[256] = acc[1]; dst[512] = acc[2]; dst[768] = acc[3];
            }
            __syncthreads();
            if (tid < 256) {      // combine0 zero-state: c = i*g (copies 0+1)
                float pi = sm[BS0O + jj], pg = sm[BS0O + 128 + jj], po = sm[BS0O + 192 + jj];
                const float* pA = sm + PO + 0 * 1024 + rr * 256;
                const float* pB = sm + PO + 1 * 1024 + rr * 256;
                pi += pA[jj] + pB[jj];
                pg += pA[128 + jj] + pB[128 + jj];
                po += pA[192 + jj] + pB[192 + jj];
                const float ig = sigm(pi), gg = tanh_(pg), og = sigm(po);
                sm[H0O + tid] = og * tanh_(ig * gg);
            }
            __syncthreads();
            if (dsub == 1) {      // cell1 partials: Wih1 . h0 -> copies 2,3
                float acc[4] = {0.f, 0.f, 0.f, 0.f};
                const float* ib = sm + H0O + dkh * 32;
#pragma unroll
                for (int k4 = 0; k4 < 8; ++k4) {
                    fma4v(acc[0], *reinterpret_cast<const float4*>(ib + 0 * 64 + k4 * 4), w[k4]);
                    fma4v(acc[1], *reinterpret_cast<const float4*>(ib + 1 * 64 + k4 * 4), w[k4]);
                    fma4v(acc[2], *reinterpret_cast<const float4*>(ib + 2 * 64 + k4 * 4), w[k4]);
                    fma4v(acc[3], *reinterpret_cast<const float4*>(ib + 3 * 64 + k4 * 4), w[k4]);
                }
                float* dst = sm + PO + (2 + dkh) * 1024 + g0;
                dst[0] = acc[0]; dst[256] = acc[1]; dst[512] = acc[2]; dst[768] = acc[3];
            }
            __syncthreads();
            if (tid < 256) {      // combine1 zero-state (copies 2+3)
                float pi = sm[BS1O + jj], pg = sm[BS1O + 128 + jj], po = sm[BS1O + 192 + jj];
                const float* pA = sm + PO + 2 * 1024 + rr * 256;
                const float* pB = sm + PO + 3 * 1024 + rr * 256;
                pi += pA[jj] + pB[jj];
                pg += pA[128 + jj] + pB[128 + jj];
                po += pA[192 + jj] + pB[192 + jj];
                const float ig = sigm(pi), gg = tanh_(pg), og = sigm(po);
                sm[H1O + tid] = og * tanh_(ig * gg);
            }
            __syncthreads();
            if (tid < 256) {      // FC
                float acc = bfc_j;
                const float4* hp = reinterpret_cast<const float4*>(sm + H1O + rr * 64);
#pragma unroll
                for (int k4 = 0; k4 < 16; ++k4) {
                    const float4 hv = hp[k4];
                    const float* wp = sm + WFCO + k4 * 256;
                    acc = fmaf(hv.x, wp[jj],       acc);
                    acc = fmaf(hv.y, wp[64 + jj],  acc);
                    acc = fmaf(hv.z, wp[128 + jj], acc);
                    acc = fmaf(hv.w, wp[192 + jj], acc);
                }
                out[(size_t)(row0 + rr) * PRED * DIM + p * DIM + jj] = acc;
                sm[DBO + tid] = acc;
            }
            __syncthreads();
        }
    }
}

// ===================== FALLBACK: proven 512-thr baseline (1810 us) ==========
#define BTHREADS 512
#define BP0O   0
#define BP1O   4096
#define BWFCO  8192
#define BH0O   12288
#define BH1O   12544
#define BDBO   12800
#define BBS0O  13056
#define BBS1O  13312
#define BBFCO  13568
#define BSMF   13632
#define BSMEM_BYTES (BSMF * 4)

extern "C" __global__ void __launch_bounds__(BTHREADS, 2)
rnn_fused_base(const float* __restrict__ x,
          const float* __restrict__ Wih0, const float* __restrict__ Whh0,
          const float* __restrict__ bih0, const float* __restrict__ bhh0,
          const float* __restrict__ Wih1, const float* __restrict__ Whh1,
          const float* __restrict__ bih1, const float* __restrict__ bhh1,
          const float* __restrict__ Wfc,  const float* __restrict__ bfc,
          float* __restrict__ out)
{
    extern __shared__ float sm[];
    const int tid = threadIdx.x;
    const int bid = blockIdx.x;
    const int grp = tid >> 7;
    const int m   = grp & 1;
    const int kh  = grp >> 1;
    const int gp  = tid & 127;
    const int g0  = gp, g1 = gp + 128;
    const int rr  = (tid & 255) >> 6;
    const int jj  = tid & 63;

    if (tid < GATES) {
        sm[BBS0O + tid] = bih0[tid] + bhh0[tid];
        sm[BBS1O + tid] = bih1[tid] + bhh1[tid];
    }
    if (tid < DIM) sm[BBFCO + tid] = bfc[tid];
    if (tid < 256) { sm[BH0O + tid] = 0.0f; sm[BH1O + tid] = 0.0f; }
    for (int idx = tid; idx < DIM * DIM; idx += BTHREADS) {
        const int j = idx >> 6, k = idx & 63;
        sm[BWFCO + (k >> 2) * 256 + (k & 3) * 64 + j] = Wfc[idx];
    }

    const float* Wsrc0 = m ? Whh0 : Wih0;
    const float* Wsrc1 = m ? Whh1 : Wih1;
    float4 w0a[8], w0b[8], w1a[8], w1b[8];
#pragma unroll
    for (int k4 = 0; k4 < 8; ++k4) {
        w0a[k4] = *reinterpret_cast<const float4*>(Wsrc0 + g0 * DIM + kh * 32 + k4 * 4);
        w0b[k4] = *reinterpret_cast<const float4*>(Wsrc0 + g1 * DIM + kh * 32 + k4 * 4);
        w1a[k4] = *reinterpret_cast<const float4*>(Wsrc1 + g0 * DIM + kh * 32 + k4 * 4);
        w1b[k4] = *reinterpret_cast<const float4*>(Wsrc1 + g1 * DIM + kh * 32 + k4 * 4);
    }
    __syncthreads();

    const int row0 = bid * 4;
    const float* xr0 = x + (size_t)(row0 + 0) * TSEQ * DIM + kh * 32;
    const float* xr1 = x + (size_t)(row0 + 1) * TSEQ * DIM + kh * 32;
    const float* xr2 = x + (size_t)(row0 + 2) * TSEQ * DIM + kh * 32;
    const float* xr3 = x + (size_t)(row0 + 3) * TSEQ * DIM + kh * 32;

    const int pb = grp * 1024;
    float c_state = 0.0f;

    for (int s = 0; s < TSEQ; ++s) {
        if (s != 0 && tid >= 256) {
            float pi = sm[BBS1O + jj],       pf = sm[BBS1O + 64 + jj];
            float pg = sm[BBS1O + 128 + jj], po = sm[BBS1O + 192 + jj];
#pragma unroll
            for (int cp = 0; cp < 4; ++cp) {
                const float* p = sm + BP1O + cp * 1024 + rr * 256;
                pi += p[jj]; pf += p[64 + jj]; pg += p[128 + jj]; po += p[192 + jj];
            }
            const float ig = sigm(pi), fg = sigm(pf), gg = tanh_(pg), og = sigm(po);
            c_state = fmaf(fg, c_state, ig * gg);
            sm[BH1O + (tid & 255)] = og * tanh_(c_state);
        }
        {
            float acc[8];
#pragma unroll
            for (int i = 0; i < 8; ++i) acc[i] = 0.0f;
            if (m == 0) {
                const int so = s * DIM;
#pragma unroll
                for (int k4 = 0; k4 < 8; ++k4) {
                    const float4 v0 = *reinterpret_cast<const float4*>(xr0 + so + k4 * 4);
                    const float4 v1 = *reinterpret_cast<const float4*>(xr1 + so + k4 * 4);
                    const float4 v2 = *reinterpret_cast<const float4*>(xr2 + so + k4 * 4);
                    const float4 v3 = *reinterpret_cast<const float4*>(xr3 + so + k4 * 4);
                    fma4v(acc[0], v0, w0a[k4]); fma4v(acc[1], v0, w0b[k4]);
                    fma4v(acc[2], v1, w0a[k4]); fma4v(acc[3], v1, w0b[k4]);
                    fma4v(acc[4], v2, w0a[k4]); fma4v(acc[5], v2, w0b[k4]);
                    fma4v(acc[6], v3, w0a[k4]); fma4v(acc[7], v3, w0b[k4]);
                }
            } else {
#pragma unroll
                for (int k4 = 0; k4 < 8; ++k4) {
                    const float4 v0 = *reinterpret_cast<const float4*>(sm + BH0O + 0 * 64 + kh * 32 + k4 * 4);
                    const float4 v1 = *reinterpret_cast<const float4*>(sm + BH0O + 1 * 64 + kh * 32 + k4 * 4);
                    const float4 v2 = *reinterpret_cast<const float4*>(sm + BH0O + 2 * 64 + kh * 32 + k4 * 4);
                    const float4 v3 = *reinterpret_cast<const float4*>(sm + BH0O + 3 * 64 + kh * 32 + k4 * 4);
                    fma4v(acc[0], v0, w0a[k4]); fma4v(acc[1], v0, w0b[k4]);
                    fma4v(acc[2], v1, w0a[k4]); fma4v(acc[3], v1, w0b[k4]);
                    fma4v(acc[4], v2, w0a[k4]); fma4v(acc[5], v2, w0b[k4]);
                    fma4v(acc[6], v3, w0a[k4]); fma4v(acc[7], v3, w0b[k4]);
                }
            }
            sm[BP0O + pb + 0 * 256 + g0] = acc[0]; sm[BP0O + pb + 0 * 256 + g1] = acc[1];
            sm[BP0O + pb + 1 * 256 + g0] = acc[2]; sm[BP0O + pb + 1 * 256 + g1] = acc[3];
            sm[BP0O + pb + 2 * 256 + g0] = acc[4]; sm[BP0O + pb + 2 * 256 + g1] = acc[5];
            sm[BP0O + pb + 3 * 256 + g0] = acc[6]; sm[BP0O + pb + 3 * 256 + g1] = acc[7];
        }
        __syncthreads();

        if (tid < 256) {
            float pi = sm[BBS0O + jj],       pf = sm[BBS0O + 64 + jj];
            float pg = sm[BBS0O + 128 + jj], po = sm[BBS0O + 192 + jj];
#pragma unroll
            for (int cp = 0; cp < 4; ++cp) {
                const float* p = sm + BP0O + cp * 1024 + rr * 256;
                pi += p[jj]; pf += p[64 + jj]; pg += p[128 + jj]; po += p[192 + jj];
            }
            const float ig = sigm(pi), fg = sigm(pf), gg = tanh_(pg), og = sigm(po);
            c_state = fmaf(fg, c_state, ig * gg);
            sm[BH0O + tid] = og * tanh_(c_state);
        }
        __syncthreads();

        {
            const int ib = m ? BH1O : BH0O;
            float acc[8];
#pragma unroll
            for (int i = 0; i < 8; ++i) acc[i] = 0.0f;
#pragma unroll
            for (int k4 = 0; k4 < 8; ++k4) {
                const float4 v0 = *reinterpret_cast<const float4*>(sm + ib + 0 * 64 + kh * 32 + k4 * 4);
                const float4 v1 = *reinterpret_cast<const float4*>(sm + ib + 1 * 64 + kh * 32 + k4 * 4);
                const float4 v2 = *reinterpret_cast<const float4*>(sm + ib + 2 * 64 + kh * 32 + k4 * 4);
                const float4 v3 = *reinterpret_cast<const float4*>(sm + ib + 3 * 64 + kh * 32 + k4 * 4);
                fma4v(acc[0], v0, w1a[k4]); fma4v(acc[1], v0, w1b[k4]);
                fma4v(acc[2], v1, w1a[k4]); fma4v(acc[3], v1, w1b[k4]);
                fma4v(acc[4], v2, w1a[k4]); fma4v(acc[5], v2, w1b[k4]);
                fma4v(acc[6], v3, w1a[k4]); fma4v(acc[7], v3, w1b[k4]);
            }
            sm[BP1O + pb + 0 * 256 + g0] = acc[0]; sm[BP1O + pb + 0 * 256 + g1] = acc[1];
            sm[BP1O + pb + 1 * 256 + g0] = acc[2]; sm[BP1O + pb + 1 * 256 + g1] = acc[3];
            sm[BP1O + pb + 2 * 256 + g0] = acc[4]; sm[BP1O + pb + 2 * 256 + g1] = acc[5];
            sm[BP1O + pb + 3 * 256 + g0] = acc[6]; sm[BP1O + pb + 3 * 256 + g1] = acc[7];
        }
        __syncthreads();
    }

    if (tid >= 256) {
        float pi = sm[BBS1O + jj],       pf = sm[BBS1O + 64 + jj];
        float pg = sm[BBS1O + 128 + jj], po = sm[BBS1O + 192 + jj];
#pragma unroll
        for (int cp = 0; cp < 4; ++cp) {
            const float* p = sm + BP1O + cp * 1024 + rr * 256;
            pi += p[jj]; pf += p[64 + jj]; pg += p[128 + jj]; po += p[192 + jj];
        }
        const float ig = sigm(pi), fg = sigm(pf), gg = tanh_(pg), og = sigm(po);
        c_state = fmaf(fg, c_state, ig * gg);
        sm[BDBO + (tid & 255)] = og * tanh_(c_state);
    }
    __syncthreads();

    const float bfc_j = sm[BBFCO + jj];

    for (int p = 0; p < PRED; ++p) {
        if (m == 0) {
            float acc[8];
#pragma unroll
            for (int i = 0; i < 8; ++i) acc[i] = 0.0f;
#pragma unroll
            for (int k4 = 0; k4 < 8; ++k4) {
                const float4 v0 = *reinterpret_cast<const float4*>(sm + BDBO + 0 * 64 + kh * 32 + k4 * 4);
                const float4 v1 = *reinterpret_cast<const float4*>(sm + BDBO + 1 * 64 + kh * 32 + k4 * 4);
                const float4 v2 = *reinterpret_cast<const float4*>(sm + BDBO + 2 * 64 + kh * 32 + k4 * 4);
                const float4 v3 = *reinterpret_cast<const float4*>(sm + BDBO + 3 * 64 + kh * 32 + k4 * 4);
                fma4v(acc[0], v0, w0a[k4]); fma4v(acc[1], v0, w0b[k4]);
                fma4v(acc[2], v1, w0a[k4]); fma4v(acc[3], v1, w0b[k4]);
                fma4v(acc[4], v2, w0a[k4]); fma4v(acc[5], v2, w0b[k4]);
                fma4v(acc[6], v3, w0a[k4]); fma4v(acc[7], v3, w0b[k4]);
            }
            sm[BP0O + pb + 0 * 256 + g0] = acc[0]; sm[BP0O + pb + 0 * 256 + g1] = acc[1];
            sm[BP0O + pb + 1 * 256 + g0] = acc[2]; sm[BP0O + pb + 1 * 256 + g1] = acc[3];
            sm[BP0O + pb + 2 * 256 + g0] = acc[4]; sm[BP0O + pb + 2 * 256 + g1] = acc[5];
            sm[BP0O + pb + 3 * 256 + g0] = acc[6]; sm[BP0O + pb + 3 * 256 + g1] = acc[7];
        }
        __syncthreads();
        if (tid < 256) {
            float pi = sm[BBS0O + jj], pg = sm[BBS0O + 128 + jj], po = sm[BBS0O + 192 + jj];
            {
                const float* pA = sm + BP0O + 0 * 1024 + rr * 256;
                const float* pB = sm + BP0O + 2 * 1024 + rr * 256;
                pi += pA[jj] + pB[jj];
                pg += pA[128 + jj] + pB[128 + jj];
                po += pA[192 + jj] + pB[192 + jj];
            }
            const float ig = sigm(pi), gg = tanh_(pg), og = sigm(po);
            sm[BH0O + tid] = og * tanh_(ig * gg);
        }
        __syncthreads();

        if (m == 0) {
            float acc[8];
#pragma unroll
            for (int i = 0; i < 8; ++i) acc[i] = 0.0f;
#pragma unroll
            for (int k4 = 0; k4 < 8; ++k4) {
                const float4 v0 = *reinterpret_cast<const float4*>(sm + BH0O + 0 * 64 + kh * 32 + k4 * 4);
                const float4 v1 = *reinterpret_cast<const float4*>(sm + BH0O + 1 * 64 + kh * 32 + k4 * 4);
                const float4 v2 = *reinterpret_cast<const float4*>(sm + BH0O + 2 * 64 + kh * 32 + k4 * 4);
                const float4 v3 = *reinterpret_cast<const float4*>(sm + BH0O + 3 * 64 + kh * 32 + k4 * 4);
                fma4v(acc[0], v0, w1a[k4]); fma4v(acc[1], v0, w1b[k4]);
                fma4v(acc[2], v1, w1a[k4]); fma4v(acc[3], v1, w1b[k4]);
                fma4v(acc[4], v2, w1a[k4]); fma4v(acc[5], v2, w1b[k4]);
                fma4v(acc[6], v3, w1a[k4]); fma4v(acc[7], v3, w1b[k4]);
            }
            sm[BP1O + pb + 0 * 256 + g0] = acc[0]; sm[BP1O + pb + 0 * 256 + g1] = acc[1];
            sm[BP1O + pb + 1 * 256 + g0] = acc[2]; sm[BP1O + pb + 1 * 256 + g1] = acc[3];
            sm[BP1O + pb + 2 * 256 + g0] = acc[4]; sm[BP1O + pb + 2 * 256 + g1] = acc[5];
            sm[BP1O + pb + 3 * 256 + g0] = acc[6]; sm[BP1O + pb + 3 * 256 + g1] = acc[7];
        }
        __syncthreads();
        if (tid >= 256) {
            float pi = sm[BBS1O + jj], pg = sm[BBS1O + 128 + jj], po = sm[BBS1O + 192 + jj];
            {
                const float* pA = sm + BP1O + 0 * 1024 + rr * 256;
                const float* pB = sm + BP1O + 2 * 1024 + rr * 256;
                pi += pA[jj] + pB[jj];
                pg += pA[128 + jj] + pB[128 + jj];
                po += pA[192 + jj] + pB[192 + jj];
            }
            const float ig = sigm(pi), gg = tanh_(pg), og = sigm(po);
            sm[BH1O + (tid & 255)] = og * tanh_(ig * gg);
        }
        __syncthreads();

        if (tid < 256) {
            float acc = bfc_j;
            const float4* hp = reinterpret_cast<const float4*>(sm + BH1O + rr * 64);
#pragma unroll
            for (int k4 = 0; k4 < 16; ++k4) {
                const float4 hv = hp[k4];
                const float* wp = sm + BWFCO + k4 * 256;
                acc = fmaf(hv.x, wp[jj],       acc);
                acc = fmaf(hv.y, wp[64 + jj],  acc);
                acc = fmaf(hv.z, wp[128 + jj], acc);
                acc = fmaf(hv.w, wp[192 + jj], acc);
            }
            out[(size_t)(row0 + rr) * PRED * DIM + p * DIM + jj] = acc;
            sm[BDBO + tid] = acc;
        }
        __syncthreads();
    }
}

extern "C" void kernel_launch(void* const* d_in, const int* in_sizes, int n_in,
                              void* d_out, int out_size, void* d_ws, size_t ws_size,
                              hipStream_t stream) {
    const float* x    = (const float*)d_in[0];
    const float* Wih0 = (const float*)d_in[1];
    const float* Whh0 = (const float*)d_in[2];
    const float* bih0 = (const float*)d_in[3];
    const float* bhh0 = (const float*)d_in[4];
    const float* Wih1 = (const float*)d_in[5];
    const float* Whh1 = (const float*)d_in[6];
    const float* bih1 = (const float*)d_in[7];
    const float* bhh1 = (const float*)d_in[8];
    const float* Wfc  = (const float*)d_in[9];
    const float* bfc  = (const float*)d_in[10];
    float* out = (float*)d_out;

    const size_t need = (size_t)NB * TSEQ * DIM * sizeof(float);  // 88.1 MB h0 buffer
    if (d_ws != nullptr && ws_size >= need) {
        hipLaunchKernelGGL(rnn_split, dim3(NB / 4), dim3(1024), SMEM_BYTES, stream,
                           x, Wih0, Whh0, bih0, bhh0, Wih1, Whh1, bih1, bhh1, Wfc, bfc,
                           out, (float*)d_ws);
    } else {
        hipLaunchKernelGGL(rnn_fused_base, dim3(NB / 4), dim3(BTHREADS), BSMEM_BYTES, stream,
                           x, Wih0, Whh0, bih0, bhh0, Wih1, Whh1, bih1, bhh1, Wfc, bfc, out);
    }
}

// Round 7
// 5223.370 us; speedup vs baseline: 3.1468x; 3.1468x over previous
//
#include <hip/hip_runtime.h>

#define NB    1024
#define TSEQ  336
#define DIM   64
#define GATES 256
#define PRED  96
#define THREADS 512

// ====================== SPLIT-PHASE, 512-THREAD KERNEL ======================
// R2-R6 findings: 1024-thr workgroups are pinned to a 64-VGPR RA budget on
// this toolchain (4/4 experiments) -> any >64-reg demand spills weights to
// scratch (40 GB HBM). 512-thr blocks honor launch_bounds ((512,2)->128 VGPR,
// baseline). So: 512 threads, 512 blocks (2 batch rows each), launch_bounds
// (512,4) -> 128-VGPR budget, and SPLIT PHASES (R6-verified structure) keep
// per-lane weights at 64 floats so demand (~100) fits. 2 blocks/CU = 4
// waves/SIMD = 2x baseline occupancy, with independent blocks overlapping at
// barriers.
//   phase1: layer 0, Wih0+Whh0 resident; h0 -> LDS + h0buf(workspace)
//   phase2: layer 1, Wih1+Whh1 resident; ih input = h0buf
//   phase3: decoder, Wih0 (lanes<256) / Wih1 (lanes>=256), zero-state cells

// LDS layout (float offsets)
#define PO    0      // partials [4 copies][2 rows][256 gates] (dec: [0..511] cell0, [1024..1535] cell1)
#define WFCO  2048   // W_fc [16][4][64] : (k4,c,j) = W[j][4k4+c]
#define H0O   6144   // [2][64]
#define H1O   6272   // [2][64]
#define DBO   6400   // [2][64] decoder feedback
#define BS0O  6528   // 256
#define BS1O  6784   // 256
#define BFCO  7040   // 64
#define SMF   7104
#define SMEM_BYTES (SMF * 4)

__device__ __forceinline__ float sigm(float v)  { return 1.0f / (1.0f + __expf(-v)); }
__device__ __forceinline__ float tanh_(float v) { return 1.0f - 2.0f / (__expf(2.0f * v) + 1.0f); }

__device__ __forceinline__ void fma4v(float& acc, const float4 xv, const float4 w) {
    acc = fmaf(xv.x, w.x, acc); acc = fmaf(xv.y, w.y, acc);
    acc = fmaf(xv.z, w.z, acc); acc = fmaf(xv.w, w.w, acc);
}

extern "C" __global__ void __launch_bounds__(THREADS, 4)
rnn_split512(const float* __restrict__ x,
             const float* __restrict__ Wih0, const float* __restrict__ Whh0,
             const float* __restrict__ bih0, const float* __restrict__ bhh0,
             const float* __restrict__ Wih1, const float* __restrict__ Whh1,
             const float* __restrict__ bih1, const float* __restrict__ bhh1,
             const float* __restrict__ Wfc,  const float* __restrict__ bfc,
             float* __restrict__ out, float* __restrict__ h0buf)
{
    extern __shared__ float sm[];
    const int tid = threadIdx.x;
    const int bid = blockIdx.x;
    const int sub = tid >> 7;          // 0..3 (wave-pair-uniform): copy index
    const int mm  = sub >> 1;          // 0: ih matvec, 1: hh matvec
    const int kh  = sub & 1;           // k-half
    const int gp  = tid & 127;
    const int g0  = gp, g1 = gp + 128; // owned gate rows
    const int rr  = (tid >> 6) & 1;    // combine row (valid for tid<128)
    const int jj  = tid & 63;          // combine hidden index
    const int row0 = bid * 2;

    // ---- prologue staging ----
    if (tid < GATES) {
        sm[BS0O + tid] = bih0[tid] + bhh0[tid];
        sm[BS1O + tid] = bih1[tid] + bhh1[tid];
    }
    if (tid < DIM) sm[BFCO + tid] = bfc[tid];
    if (tid < 128) { sm[H0O + tid] = 0.0f; sm[H1O + tid] = 0.0f; }
    for (int idx = tid; idx < DIM * DIM; idx += THREADS) {   // W_fc: (k4,c,j)
        const int j = idx >> 6, k = idx & 63;
        sm[WFCO + (k >> 2) * 256 + (k & 3) * 64 + j] = Wfc[idx];
    }

    // ================= phase 1: layer 0 (Wih0 + Whh0) =================
    {
        const float* Wsrc = mm ? Whh0 : Wih0;
        float4 wa[8], wb[8];   // 64 floats/lane
#pragma unroll
        for (int k4 = 0; k4 < 8; ++k4) {
            wa[k4] = *reinterpret_cast<const float4*>(Wsrc + g0 * DIM + kh * 32 + k4 * 4);
            wb[k4] = *reinterpret_cast<const float4*>(Wsrc + g1 * DIM + kh * 32 + k4 * 4);
        }
        __syncthreads();

        const float* xr0 = x + (size_t)(row0 + 0) * TSEQ * DIM + kh * 32;
        const float* xr1 = x + (size_t)(row0 + 1) * TSEQ * DIM + kh * 32;
        float c0 = 0.0f;

        for (int s = 0; s < TSEQ; ++s) {
            float acc[4] = {0.f, 0.f, 0.f, 0.f};
            if (mm == 0) {          // ih: wave-uniform global x loads
                const int so = s * DIM;
#pragma unroll
                for (int k4 = 0; k4 < 8; ++k4) {
                    const float4 v0 = *reinterpret_cast<const float4*>(xr0 + so + k4 * 4);
                    const float4 v1 = *reinterpret_cast<const float4*>(xr1 + so + k4 * 4);
                    fma4v(acc[0], v0, wa[k4]); fma4v(acc[1], v0, wb[k4]);
                    fma4v(acc[2], v1, wa[k4]); fma4v(acc[3], v1, wb[k4]);
                }
            } else {                // hh: wave-uniform LDS broadcasts
                const float* ib = sm + H0O + kh * 32;
#pragma unroll
                for (int k4 = 0; k4 < 8; ++k4) {
                    const float4 v0 = *reinterpret_cast<const float4*>(ib + 0 * 64 + k4 * 4);
                    const float4 v1 = *reinterpret_cast<const float4*>(ib + 1 * 64 + k4 * 4);
                    fma4v(acc[0], v0, wa[k4]); fma4v(acc[1], v0, wb[k4]);
                    fma4v(acc[2], v1, wa[k4]); fma4v(acc[3], v1, wb[k4]);
                }
            }
            float* dst = sm + PO + sub * 512 + g0;   // [copy][row][gate]
            dst[0] = acc[0]; dst[128] = acc[1]; dst[256] = acc[2]; dst[384] = acc[3];
            __syncthreads();

            if (tid < 128) {        // combine: 4 copies + bias
                float pi = sm[BS0O + jj],       pf = sm[BS0O + 64 + jj];
                float pg = sm[BS0O + 128 + jj], po = sm[BS0O + 192 + jj];
#pragma unroll
                for (int cp = 0; cp < 4; ++cp) {
                    const float* p = sm + PO + cp * 512 + rr * 256;
                    pi += p[jj]; pf += p[64 + jj]; pg += p[128 + jj]; po += p[192 + jj];
                }
                const float ig = sigm(pi), fg = sigm(pf), gg = tanh_(pg), og = sigm(po);
                c0 = fmaf(fg, c0, ig * gg);
                const float h = og * tanh_(c0);
                sm[H0O + tid] = h;
                h0buf[(size_t)(row0 + rr) * TSEQ * DIM + s * DIM + jj] = h;
            }
            __syncthreads();
        }
    }

    // ================= phase 2: layer 1 (Wih1 + Whh1) =================
    {
        const float* Wsrc = mm ? Whh1 : Wih1;
        float4 wa[8], wb[8];
#pragma unroll
        for (int k4 = 0; k4 < 8; ++k4) {
            wa[k4] = *reinterpret_cast<const float4*>(Wsrc + g0 * DIM + kh * 32 + k4 * 4);
            wb[k4] = *reinterpret_cast<const float4*>(Wsrc + g1 * DIM + kh * 32 + k4 * 4);
        }
        const float* hr0 = h0buf + (size_t)(row0 + 0) * TSEQ * DIM + kh * 32;
        const float* hr1 = h0buf + (size_t)(row0 + 1) * TSEQ * DIM + kh * 32;
        float c1 = 0.0f;
        // H1O still zero from prologue (phase 1 never writes it)

        for (int s = 0; s < TSEQ; ++s) {
            float acc[4] = {0.f, 0.f, 0.f, 0.f};
            if (mm == 0) {          // ih: own h0 writes (same block, barrier-ordered)
                const int so = s * DIM;
#pragma unroll
                for (int k4 = 0; k4 < 8; ++k4) {
                    const float4 v0 = *reinterpret_cast<const float4*>(hr0 + so + k4 * 4);
                    const float4 v1 = *reinterpret_cast<const float4*>(hr1 + so + k4 * 4);
                    fma4v(acc[0], v0, wa[k4]); fma4v(acc[1], v0, wb[k4]);
                    fma4v(acc[2], v1, wa[k4]); fma4v(acc[3], v1, wb[k4]);
                }
            } else {                // hh: h1_{s-1} from LDS
                const float* ib = sm + H1O + kh * 32;
#pragma unroll
                for (int k4 = 0; k4 < 8; ++k4) {
                    const float4 v0 = *reinterpret_cast<const float4*>(ib + 0 * 64 + k4 * 4);
                    const float4 v1 = *reinterpret_cast<const float4*>(ib + 1 * 64 + k4 * 4);
                    fma4v(acc[0], v0, wa[k4]); fma4v(acc[1], v0, wb[k4]);
                    fma4v(acc[2], v1, wa[k4]); fma4v(acc[3], v1, wb[k4]);
                }
            }
            float* dst = sm + PO + sub * 512 + g0;
            dst[0] = acc[0]; dst[128] = acc[1]; dst[256] = acc[2]; dst[384] = acc[3];
            __syncthreads();

            if (tid < 128) {
                float pi = sm[BS1O + jj],       pf = sm[BS1O + 64 + jj];
                float pg = sm[BS1O + 128 + jj], po = sm[BS1O + 192 + jj];
#pragma unroll
                for (int cp = 0; cp < 4; ++cp) {
                    const float* p = sm + PO + cp * 512 + rr * 256;
                    pi += p[jj]; pf += p[64 + jj]; pg += p[128 + jj]; po += p[192 + jj];
                }
                const float ig = sigm(pi), fg = sigm(pf), gg = tanh_(pg), og = sigm(po);
                c1 = fmaf(fg, c1, ig * gg);
                sm[H1O + tid] = og * tanh_(c1);
            }
            __syncthreads();
        }
    }

    // ================= phase 3: decoder (96 zero-state steps) =================
    {
        const int dsub = tid >> 8;          // 0: Wih0 team (lanes 0-255), 1: Wih1 team
        const int g0d  = tid & 255;         // owned gate row, full K=64
        const float* Wsrc = dsub ? Wih1 : Wih0;
        float4 wd[16];                      // 64 floats/lane
#pragma unroll
        for (int k4 = 0; k4 < 16; ++k4)
            wd[k4] = *reinterpret_cast<const float4*>(Wsrc + g0d * DIM + k4 * 4);

        if (tid < 128) sm[DBO + tid] = sm[H1O + tid];   // db = h1_last
        __syncthreads();
        const float bfc_j = sm[BFCO + jj];

        for (int p = 0; p < PRED; ++p) {
            if (dsub == 0) {      // cell0 partials: Wih0 . db (single copy)
                float acc0 = 0.f, acc1 = 0.f;
#pragma unroll
                for (int k4 = 0; k4 < 16; ++k4) {
                    const float4 v0 = *reinterpret_cast<const float4*>(sm + DBO + 0 * 64 + k4 * 4);
                    const float4 v1 = *reinterpret_cast<const float4*>(sm + DBO + 1 * 64 + k4 * 4);
                    fma4v(acc0, v0, wd[k4]);
                    fma4v(acc1, v1, wd[k4]);
                }
                sm[PO + g0d]       = acc0;
                sm[PO + 256 + g0d] = acc1;
            }
            __syncthreads();
            if (tid < 128) {      // combine0 zero-state: c = i*g
                const float* pp = sm + PO + rr * 256;
                const float pi = sm[BS0O + jj] + pp[jj];
                const float pg = sm[BS0O + 128 + jj] + pp[128 + jj];
                const float po = sm[BS0O + 192 + jj] + pp[192 + jj];
                const float ig = sigm(pi), gg = tanh_(pg), og = sigm(po);
                sm[H0O + tid] = og * tanh_(ig * gg);
            }
            __syncthreads();
            if (dsub == 1) {      // cell1 partials: Wih1 . h0 (single copy)
                float acc0 = 0.f, acc1 = 0.f;
#pragma unroll
                for (int k4 = 0; k4 < 16; ++k4) {
                    const float4 v0 = *reinterpret_cast<const float4*>(sm + H0O + 0 * 64 + k4 * 4);
                    const float4 v1 = *reinterpret_cast<const float4*>(sm + H0O + 1 * 64 + k4 * 4);
                    fma4v(acc0, v0, wd[k4]);
                    fma4v(acc1, v1, wd[k4]);
                }
                sm[PO + 1024 + g0d]       = acc0;
                sm[PO + 1024 + 256 + g0d] = acc1;
            }
            __syncthreads();
            if (tid < 128) {      // combine1 zero-state + FC (fused: wave-local H1 row)
                const float* pp = sm + PO + 1024 + rr * 256;
                const float pi = sm[BS1O + jj] + pp[jj];
                const float pg = sm[BS1O + 128 + jj] + pp[128 + jj];
                const float po = sm[BS1O + 192 + jj] + pp[192 + jj];
                const float ig = sigm(pi), gg = tanh_(pg), og = sigm(po);
                sm[H1O + tid] = og * tanh_(ig * gg);
                // FC: row rr of H1 is produced entirely by THIS wave (lanes
                // rr*64..rr*64+63) -> intra-wave LDS ordering (lgkmcnt), no barrier.
                float acc = bfc_j;
                const float4* hp = reinterpret_cast<const float4*>(sm + H1O + rr * 64);
#pragma unroll
                for (int k4 = 0; k4 < 16; ++k4) {
                    const float4 hv = hp[k4];
                    const float* wp = sm + WFCO + k4 * 256;
                    acc = fmaf(hv.x, wp[jj],       acc);
                    acc = fmaf(hv.y, wp[64 + jj],  acc);
                    acc = fmaf(hv.z, wp[128 + jj], acc);
                    acc = fmaf(hv.w, wp[192 + jj], acc);
                }
                out[(size_t)(row0 + rr) * PRED * DIM + p * DIM + jj] = acc;
                sm[DBO + tid] = acc;
            }
            __syncthreads();
        }
    }
}

// ===================== FALLBACK: proven 512-thr baseline (1810 us) ==========
#define BP0O   0
#define BP1O   4096
#define BWFCO  8192
#define BH0O   12288
#define BH1O   12544
#define BDBO   12800
#define BBS0O  13056
#define BBS1O  13312
#define BBFCO  13568
#define BSMF   13632
#define BSMEM_BYTES (BSMF * 4)

extern "C" __global__ void __launch_bounds__(512, 2)
rnn_fused_base(const float* __restrict__ x,
          const float* __restrict__ Wih0, const float* __restrict__ Whh0,
          const float* __restrict__ bih0, const float* __restrict__ bhh0,
          const float* __restrict__ Wih1, const float* __restrict__ Whh1,
          const float* __restrict__ bih1, const float* __restrict__ bhh1,
          const float* __restrict__ Wfc,  const float* __restrict__ bfc,
          float* __restrict__ out)
{
    extern __shared__ float sm[];
    const int tid = threadIdx.x;
    const int bid = blockIdx.x;
    const int grp = tid >> 7;
    const int m   = grp & 1;
    const int kh  = grp >> 1;
    const int gp  = tid & 127;
    const int g0  = gp, g1 = gp + 128;
    const int rr  = (tid & 255) >> 6;
    const int jj  = tid & 63;

    if (tid < GATES) {
        sm[BBS0O + tid] = bih0[tid] + bhh0[tid];
        sm[BBS1O + tid] = bih1[tid] + bhh1[tid];
    }
    if (tid < DIM) sm[BBFCO + tid] = bfc[tid];
    if (tid < 256) { sm[BH0O + tid] = 0.0f; sm[BH1O + tid] = 0.0f; }
    for (int idx = tid; idx < DIM * DIM; idx += 512) {
        const int j = idx >> 6, k = idx & 63;
        sm[BWFCO + (k >> 2) * 256 + (k & 3) * 64 + j] = Wfc[idx];
    }

    const float* Wsrc0 = m ? Whh0 : Wih0;
    const float* Wsrc1 = m ? Whh1 : Wih1;
    float4 w0a[8], w0b[8], w1a[8], w1b[8];
#pragma unroll
    for (int k4 = 0; k4 < 8; ++k4) {
        w0a[k4] = *reinterpret_cast<const float4*>(Wsrc0 + g0 * DIM + kh * 32 + k4 * 4);
        w0b[k4] = *reinterpret_cast<const float4*>(Wsrc0 + g1 * DIM + kh * 32 + k4 * 4);
        w1a[k4] = *reinterpret_cast<const float4*>(Wsrc1 + g0 * DIM + kh * 32 + k4 * 4);
        w1b[k4] = *reinterpret_cast<const float4*>(Wsrc1 + g1 * DIM + kh * 32 + k4 * 4);
    }
    __syncthreads();

    const int row0 = bid * 4;
    const float* xr0 = x + (size_t)(row0 + 0) * TSEQ * DIM + kh * 32;
    const float* xr1 = x + (size_t)(row0 + 1) * TSEQ * DIM + kh * 32;
    const float* xr2 = x + (size_t)(row0 + 2) * TSEQ * DIM + kh * 32;
    const float* xr3 = x + (size_t)(row0 + 3) * TSEQ * DIM + kh * 32;

    const int pb = grp * 1024;
    float c_state = 0.0f;

    for (int s = 0; s < TSEQ; ++s) {
        if (s != 0 && tid >= 256) {
            float pi = sm[BBS1O + jj],       pf = sm[BBS1O + 64 + jj];
            float pg = sm[BBS1O + 128 + jj], po = sm[BBS1O + 192 + jj];
#pragma unroll
            for (int cp = 0; cp < 4; ++cp) {
                const float* p = sm + BP1O + cp * 1024 + rr * 256;
                pi += p[jj]; pf += p[64 + jj]; pg += p[128 + jj]; po += p[192 + jj];
            }
            const float ig = sigm(pi), fg = sigm(pf), gg = tanh_(pg), og = sigm(po);
            c_state = fmaf(fg, c_state, ig * gg);
            sm[BH1O + (tid & 255)] = og * tanh_(c_state);
        }
        {
            float acc[8];
#pragma unroll
            for (int i = 0; i < 8; ++i) acc[i] = 0.0f;
            if (m == 0) {
                const int so = s * DIM;
#pragma unroll
                for (int k4 = 0; k4 < 8; ++k4) {
                    const float4 v0 = *reinterpret_cast<const float4*>(xr0 + so + k4 * 4);
                    const float4 v1 = *reinterpret_cast<const float4*>(xr1 + so + k4 * 4);
                    const float4 v2 = *reinterpret_cast<const float4*>(xr2 + so + k4 * 4);
                    const float4 v3 = *reinterpret_cast<const float4*>(xr3 + so + k4 * 4);
                    fma4v(acc[0], v0, w0a[k4]); fma4v(acc[1], v0, w0b[k4]);
                    fma4v(acc[2], v1, w0a[k4]); fma4v(acc[3], v1, w0b[k4]);
                    fma4v(acc[4], v2, w0a[k4]); fma4v(acc[5], v2, w0b[k4]);
                    fma4v(acc[6], v3, w0a[k4]); fma4v(acc[7], v3, w0b[k4]);
                }
            } else {
#pragma unroll
                for (int k4 = 0; k4 < 8; ++k4) {
                    const float4 v0 = *reinterpret_cast<const float4*>(sm + BH0O + 0 * 64 + kh * 32 + k4 * 4);
                    const float4 v1 = *reinterpret_cast<const float4*>(sm + BH0O + 1 * 64 + kh * 32 + k4 * 4);
                    const float4 v2 = *reinterpret_cast<const float4*>(sm + BH0O + 2 * 64 + kh * 32 + k4 * 4);
                    const float4 v3 = *reinterpret_cast<const float4*>(sm + BH0O + 3 * 64 + kh * 32 + k4 * 4);
                    fma4v(acc[0], v0, w0a[k4]); fma4v(acc[1], v0, w0b[k4]);
                    fma4v(acc[2], v1, w0a[k4]); fma4v(acc[3], v1, w0b[k4]);
                    fma4v(acc[4], v2, w0a[k4]); fma4v(acc[5], v2, w0b[k4]);
                    fma4v(acc[6], v3, w0a[k4]); fma4v(acc[7], v3, w0b[k4]);
                }
            }
            sm[BP0O + pb + 0 * 256 + g0] = acc[0]; sm[BP0O + pb + 0 * 256 + g1] = acc[1];
            sm[BP0O + pb + 1 * 256 + g0] = acc[2]; sm[BP0O + pb + 1 * 256 + g1] = acc[3];
            sm[BP0O + pb + 2 * 256 + g0] = acc[4]; sm[BP0O + pb + 2 * 256 + g1] = acc[5];
            sm[BP0O + pb + 3 * 256 + g0] = acc[6]; sm[BP0O + pb + 3 * 256 + g1] = acc[7];
        }
        __syncthreads();

        if (tid < 256) {
            float pi = sm[BBS0O + jj],       pf = sm[BBS0O + 64 + jj];
            float pg = sm[BBS0O + 128 + jj], po = sm[BBS0O + 192 + jj];
#pragma unroll
            for (int cp = 0; cp < 4; ++cp) {
                const float* p = sm + BP0O + cp * 1024 + rr * 256;
                pi += p[jj]; pf += p[64 + jj]; pg += p[128 + jj]; po += p[192 + jj];
            }
            const float ig = sigm(pi), fg = sigm(pf), gg = tanh_(pg), og = sigm(po);
            c_state = fmaf(fg, c_state, ig * gg);
            sm[BH0O + tid] = og * tanh_(c_state);
        }
        __syncthreads();

        {
            const int ib = m ? BH1O : BH0O;
            float acc[8];
#pragma unroll
            for (int i = 0; i < 8; ++i) acc[i] = 0.0f;
#pragma unroll
            for (int k4 = 0; k4 < 8; ++k4) {
                const float4 v0 = *reinterpret_cast<const float4*>(sm + ib + 0 * 64 + kh * 32 + k4 * 4);
                const float4 v1 = *reinterpret_cast<const float4*>(sm + ib + 1 * 64 + kh * 32 + k4 * 4);
                const float4 v2 = *reinterpret_cast<const float4*>(sm + ib + 2 * 64 + kh * 32 + k4 * 4);
                const float4 v3 = *reinterpret_cast<const float4*>(sm + ib + 3 * 64 + kh * 32 + k4 * 4);
                fma4v(acc[0], v0, w1a[k4]); fma4v(acc[1], v0, w1b[k4]);
                fma4v(acc[2], v1, w1a[k4]); fma4v(acc[3], v1, w1b[k4]);
                fma4v(acc[4], v2, w1a[k4]); fma4v(acc[5], v2, w1b[k4]);
                fma4v(acc[6], v3, w1a[k4]); fma4v(acc[7], v3, w1b[k4]);
            }
            sm[BP1O + pb + 0 * 256 + g0] = acc[0]; sm[BP1O + pb + 0 * 256 + g1] = acc[1];
            sm[BP1O + pb + 1 * 256 + g0] = acc[2]; sm[BP1O + pb + 1 * 256 + g1] = acc[3];
            sm[BP1O + pb + 2 * 256 + g0] = acc[4]; sm[BP1O + pb + 2 * 256 + g1] = acc[5];
            sm[BP1O + pb + 3 * 256 + g0] = acc[6]; sm[BP1O + pb + 3 * 256 + g1] = acc[7];
        }
        __syncthreads();
    }

    if (tid >= 256) {
        float pi = sm[BBS1O + jj],       pf = sm[BBS1O + 64 + jj];
        float pg = sm[BBS1O + 128 + jj], po = sm[BBS1O + 192 + jj];
#pragma unroll
        for (int cp = 0; cp < 4; ++cp) {
            const float* p = sm + BP1O + cp * 1024 + rr * 256;
            pi += p[jj]; pf += p[64 + jj]; pg += p[128 + jj]; po += p[192 + jj];
        }
        const float ig = sigm(pi), fg = sigm(pf), gg = tanh_(pg), og = sigm(po);
        c_state = fmaf(fg, c_state, ig * gg);
        sm[BDBO + (tid & 255)] = og * tanh_(c_state);
    }
    __syncthreads();

    const float bfc_j = sm[BBFCO + jj];

    for (int p = 0; p < PRED; ++p) {
        if (m == 0) {
            float acc[8];
#pragma unroll
            for (int i = 0; i < 8; ++i) acc[i] = 0.0f;
#pragma unroll
            for (int k4 = 0; k4 < 8; ++k4) {
                const float4 v0 = *reinterpret_cast<const float4*>(sm + BDBO + 0 * 64 + kh * 32 + k4 * 4);
                const float4 v1 = *reinterpret_cast<const float4*>(sm + BDBO + 1 * 64 + kh * 32 + k4 * 4);
                const float4 v2 = *reinterpret_cast<const float4*>(sm + BDBO + 2 * 64 + kh * 32 + k4 * 4);
                const float4 v3 = *reinterpret_cast<const float4*>(sm + BDBO + 3 * 64 + kh * 32 + k4 * 4);
                fma4v(acc[0], v0, w0a[k4]); fma4v(acc[1], v0, w0b[k4]);
                fma4v(acc[2], v1, w0a[k4]); fma4v(acc[3], v1, w0b[k4]);
                fma4v(acc[4], v2, w0a[k4]); fma4v(acc[5], v2, w0b[k4]);
                fma4v(acc[6], v3, w0a[k4]); fma4v(acc[7], v3, w0b[k4]);
            }
            sm[BP0O + pb + 0 * 256 + g0] = acc[0]; sm[BP0O + pb + 0 * 256 + g1] = acc[1];
            sm[BP0O + pb + 1 * 256 + g0] = acc[2]; sm[BP0O + pb + 1 * 256 + g1] = acc[3];
            sm[BP0O + pb + 2 * 256 + g0] = acc[4]; sm[BP0O + pb + 2 * 256 + g1] = acc[5];
            sm[BP0O + pb + 3 * 256 + g0] = acc[6]; sm[BP0O + pb + 3 * 256 + g1] = acc[7];
        }
        __syncthreads();
        if (tid < 256) {
            float pi = sm[BBS0O + jj], pg = sm[BBS0O + 128 + jj], po = sm[BBS0O + 192 + jj];
            {
                const float* pA = sm + BP0O + 0 * 1024 + rr * 256;
                const float* pB = sm + BP0O + 2 * 1024 + rr * 256;
                pi += pA[jj] + pB[jj];
                pg += pA[128 + jj] + pB[128 + jj];
                po += pA[192 + jj] + pB[192 + jj];
            }
            const float ig = sigm(pi), gg = tanh_(pg), og = sigm(po);
            sm[BH0O + tid] = og * tanh_(ig * gg);
        }
        __syncthreads();

        if (m == 0) {
            float acc[8];
#pragma unroll
            for (int i = 0; i < 8; ++i) acc[i] = 0.0f;
#pragma unroll
            for (int k4 = 0; k4 < 8; ++k4) {
                const float4 v0 = *reinterpret_cast<const float4*>(sm + BH0O + 0 * 64 + kh * 32 + k4 * 4);
                const float4 v1 = *reinterpret_cast<const float4*>(sm + BH0O + 1 * 64 + kh * 32 + k4 * 4);
                const float4 v2 = *reinterpret_cast<const float4*>(sm + BH0O + 2 * 64 + kh * 32 + k4 * 4);
                const float4 v3 = *reinterpret_cast<const float4*>(sm + BH0O + 3 * 64 + kh * 32 + k4 * 4);
                fma4v(acc[0], v0, w1a[k4]); fma4v(acc[1], v0, w1b[k4]);
                fma4v(acc[2], v1, w1a[k4]); fma4v(acc[3], v1, w1b[k4]);
                fma4v(acc[4], v2, w1a[k4]); fma4v(acc[5], v2, w1b[k4]);
                fma4v(acc[6], v3, w1a[k4]); fma4v(acc[7], v3, w1b[k4]);
            }
            sm[BP1O + pb + 0 * 256 + g0] = acc[0]; sm[BP1O + pb + 0 * 256 + g1] = acc[1];
            sm[BP1O + pb + 1 * 256 + g0] = acc[2]; sm[BP1O + pb + 1 * 256 + g1] = acc[3];
            sm[BP1O + pb + 2 * 256 + g0] = acc[4]; sm[BP1O + pb + 2 * 256 + g1] = acc[5];
            sm[BP1O + pb + 3 * 256 + g0] = acc[6]; sm[BP1O + pb + 3 * 256 + g1] = acc[7];
        }
        __syncthreads();
        if (tid >= 256) {
            float pi = sm[BBS1O + jj], pg = sm[BBS1O + 128 + jj], po = sm[BBS1O + 192 + jj];
            {
                const float* pA = sm + BP1O + 0 * 1024 + rr * 256;
                const float* pB = sm + BP1O + 2 * 1024 + rr * 256;
                pi += pA[jj] + pB[jj];
                pg += pA[128 + jj] + pB[128 + jj];
                po += pA[192 + jj] + pB[192 + jj];
            }
            const float ig = sigm(pi), gg = tanh_(pg), og = sigm(po);
            sm[BH1O + (tid & 255)] = og * tanh_(ig * gg);
        }
        __syncthreads();

        if (tid < 256) {
            float acc = bfc_j;
            const float4* hp = reinterpret_cast<const float4*>(sm + BH1O + rr * 64);
#pragma unroll
            for (int k4 = 0; k4 < 16; ++k4) {
                const float4 hv = hp[k4];
                const float* wp = sm + BWFCO + k4 * 256;
                acc = fmaf(hv.x, wp[jj],       acc);
                acc = fmaf(hv.y, wp[64 + jj],  acc);
                acc = fmaf(hv.z, wp[128 + jj], acc);
                acc = fmaf(hv.w, wp[192 + jj], acc);
            }
            out[(size_t)(row0 + rr) * PRED * DIM + p * DIM + jj] = acc;
            sm[BDBO + tid] = acc;
        }
        __syncthreads();
    }
}

extern "C" void kernel_launch(void* const* d_in, const int* in_sizes, int n_in,
                              void* d_out, int out_size, void* d_ws, size_t ws_size,
                              hipStream_t stream) {
    const float* x    = (const float*)d_in[0];
    const float* Wih0 = (const float*)d_in[1];
    const float* Whh0 = (const float*)d_in[2];
    const float* bih0 = (const float*)d_in[3];
    const float* bhh0 = (const float*)d_in[4];
    const float* Wih1 = (const float*)d_in[5];
    const float* Whh1 = (const float*)d_in[6];
    const float* bih1 = (const float*)d_in[7];
    const float* bhh1 = (const float*)d_in[8];
    const float* Wfc  = (const float*)d_in[9];
    const float* bfc  = (const float*)d_in[10];
    float* out = (float*)d_out;

    const size_t need = (size_t)NB * TSEQ * DIM * sizeof(float);  // 88.1 MB h0 buffer
    if (d_ws != nullptr && ws_size >= need) {
        hipLaunchKernelGGL(rnn_split512, dim3(NB / 2), dim3(THREADS), SMEM_BYTES, stream,
                           x, Wih0, Whh0, bih0, bhh0, Wih1, Whh1, bih1, bhh1, Wfc, bfc,
                           out, (float*)d_ws);
    } else {
        hipLaunchKernelGGL(rnn_fused_base, dim3(NB / 4), dim3(512), BSMEM_BYTES, stream,
                           x, Wih0, Whh0, bih0, bhh0, Wih1, Whh1, bih1, bhh1, Wfc, bfc, out);
    }
}

// Round 8
// 1427.747 us; speedup vs baseline: 11.5126x; 3.6585x over previous
//
#include <hip/hip_runtime.h>

#define NB    1024
#define TSEQ  336
#define DIM   64
#define GATES 256
#define PRED  96

// ========================= MULTI-KERNEL PIPELINE ============================
// R2-R7 lesson: total reg budget = 512 / launch_bounds-min-waves (V+A split);
// demand must stay under it INCLUDING load hoisting (~32 extra regs in
// unrolled global-load loops). So: one weight matrix per resident kernel
// (32 floats/lane at 512 thr), LDS-sourced inputs, and the ih parts pulled
// out of the recurrence entirely as stream-ordered GEMM launches (stream
// order = inter-phase sync; reference does the same einsum hoist).
//   1. gemm_pre:  pre = in @ W_ih^T + (b_ih+b_hh)      [parallel]
//   2. lstm_recur: h_t = LSTM(pre[t], Whh, h, c)       [hh-only resident]
//   3/4. repeat for layer 1 (pre buffer reused)
//   5. lstm_dec: 96 zero-state steps (R7 phase-3 structure, standalone)
// Workspace tiers: time-chunk pre (336/168/112) -> 441/265/207 MB; else
// fall back to the proven 1810us baseline.

__device__ __forceinline__ float sigm(float v)  { return 1.0f / (1.0f + __expf(-v)); }
__device__ __forceinline__ float tanh_(float v) { return 1.0f - 2.0f / (__expf(2.0f * v) + 1.0f); }

__device__ __forceinline__ void fma4v(float& acc, const float4 xv, const float4 w) {
    acc = fmaf(xv.x, w.x, acc); acc = fmaf(xv.y, w.y, acc);
    acc = fmaf(xv.z, w.z, acc); acc = fmaf(xv.w, w.w, acc);
}

// ---------------- kernel 1: pre = in @ W^T + ba + bb ----------------
// grid: 1024 blocks (one batch row). 512 thr: lane = (gate g, k-half kh),
// 32 weight floats/lane. x tile (8 steps) staged in LDS double-buffered.
extern "C" __global__ void __launch_bounds__(512, 4)
gemm_pre(const float* __restrict__ in,   // [1024][TSEQ][64], pre-offset by t0*64
         const float* __restrict__ W,    // [256][64]
         const float* __restrict__ ba, const float* __restrict__ bb,
         float* __restrict__ pre,        // [1024][tcount][256]
         int tcount)
{
    __shared__ __align__(16) float xt[2][512];
    __shared__ __align__(16) float pp[2 * 2048];   // [kh][t8*256+g]
    const int tid = threadIdx.x;
    const int row = blockIdx.x;
    const int g   = tid & 255;
    const int kh  = tid >> 8;

    float4 w[8];
#pragma unroll
    for (int k4 = 0; k4 < 8; ++k4)
        w[k4] = *reinterpret_cast<const float4*>(W + g * DIM + kh * 32 + k4 * 4);
    const float bs = ba[g] + bb[g];

    const float* rin  = in  + (size_t)row * (TSEQ * DIM);
    float*       rout = pre + (size_t)row * tcount * GATES;
    const int ntile = tcount >> 3;

    xt[0][tid] = rin[tid];
    __syncthreads();
    for (int tile = 0; tile < ntile; ++tile) {
        const int cur = tile & 1;
        float pa[8];
#pragma unroll
        for (int t8 = 0; t8 < 8; ++t8) {
            const float* xb = &xt[cur][t8 * 64 + kh * 32];
            float a = 0.f;
#pragma unroll
            for (int k4 = 0; k4 < 8; ++k4)
                fma4v(a, *reinterpret_cast<const float4*>(xb + k4 * 4), w[k4]);
            pa[t8] = a;
        }
#pragma unroll
        for (int t8 = 0; t8 < 8; ++t8)
            pp[kh * 2048 + t8 * 256 + g] = pa[t8];
        if (tile + 1 < ntile)                       // prefetch next x tile
            xt[cur ^ 1][tid] = rin[(tile + 1) * 512 + tid];
        __syncthreads();
        const int tb = tile * 8;
#pragma unroll
        for (int q = 0; q < 4; ++q) {               // combine kh pairs + store
            const int t8 = q * 2 + kh;
            rout[(size_t)(tb + t8) * GATES + g] =
                pp[t8 * 256 + g] + pp[2048 + t8 * 256 + g] + bs;
        }
        __syncthreads();
    }
}

// ---------------- kernel 2: hh-only LSTM recurrence ----------------
// grid: 512 blocks (2 rows each). 512 thr: (g, kh), Whh 32 floats/lane.
// pre reads prefetched 2 steps ahead on combine lanes (tid<128).
extern "C" __global__ void __launch_bounds__(512, 4)
lstm_recur(const float* __restrict__ pre, int tcount, int t0,
           const float* __restrict__ Whh,
           float* __restrict__ hseq,               // [1024][TSEQ][64] or null
           float* __restrict__ hstate, float* __restrict__ cstate, // [1024][64]
           int zero_init)
{
    __shared__ __align__(16) float Hs[128];        // h for 2 rows
    __shared__ __align__(16) float Ps[1024];       // partials [kh][row][256]
    const int tid = threadIdx.x;
    const int r0  = blockIdx.x * 2;
    const int g   = tid & 255;
    const int kh  = tid >> 8;
    const int rr  = (tid >> 6) & 1;                // combine lane row (tid<128)
    const int jj  = tid & 63;

    float4 w[8];
#pragma unroll
    for (int k4 = 0; k4 < 8; ++k4)
        w[k4] = *reinterpret_cast<const float4*>(Whh + g * DIM + kh * 32 + k4 * 4);

    const size_t prow = (size_t)tcount * GATES;
    float c = 0.f;
    float pvA0 = 0.f, pvA1 = 0.f, pvA2 = 0.f, pvA3 = 0.f;   // pre[t]
    float pvB0 = 0.f, pvB1 = 0.f, pvB2 = 0.f, pvB3 = 0.f;   // pre[t+1]
    if (tid < 128) {
        if (zero_init) Hs[tid] = 0.f;
        else { Hs[tid] = hstate[(r0 + rr) * DIM + jj]; c = cstate[(r0 + rr) * DIM + jj]; }
        const float* p0 = pre + (size_t)(r0 + rr) * prow + jj;
        pvA0 = p0[0]; pvA1 = p0[64]; pvA2 = p0[128]; pvA3 = p0[192];
        const float* p1 = p0 + GATES;
        pvB0 = p1[0]; pvB1 = p1[64]; pvB2 = p1[128]; pvB3 = p1[192];
    }
    __syncthreads();

    float hlast = 0.f;
    for (int t = 0; t < tcount; ++t) {
        // matvec (all lanes): 2 rows x 32 MAC from uniform LDS broadcasts
        float a0 = 0.f, a1 = 0.f;
        const float* hb0 = Hs + kh * 32;
        const float* hb1 = Hs + 64 + kh * 32;
#pragma unroll
        for (int k4 = 0; k4 < 8; ++k4) {
            fma4v(a0, *reinterpret_cast<const float4*>(hb0 + k4 * 4), w[k4]);
            fma4v(a1, *reinterpret_cast<const float4*>(hb1 + k4 * 4), w[k4]);
        }
        Ps[kh * 512 + g]       = a0;
        Ps[kh * 512 + 256 + g] = a1;
        __syncthreads();

        if (tid < 128) {
            float xi = pvA0, xf = pvA1, xg = pvA2, xo = pvA3;
            pvA0 = pvB0; pvA1 = pvB1; pvA2 = pvB2; pvA3 = pvB3;
            if (t + 2 < tcount) {                   // prefetch pre[t+2]
                const float* pp = pre + (size_t)(r0 + rr) * prow + (size_t)(t + 2) * GATES + jj;
                pvB0 = pp[0]; pvB1 = pp[64]; pvB2 = pp[128]; pvB3 = pp[192];
            }
            const float* q0 = Ps + rr * 256 + jj;           // kh=0 partials
            const float* q1 = Ps + 512 + rr * 256 + jj;     // kh=1 partials
            xi += q0[0]   + q1[0];
            xf += q0[64]  + q1[64];
            xg += q0[128] + q1[128];
            xo += q0[192] + q1[192];
            const float ig = sigm(xi), fg = sigm(xf), gg = tanh_(xg), og = sigm(xo);
            c = fmaf(fg, c, ig * gg);
            const float h = og * tanh_(c);
            hlast = h;
            Hs[tid] = h;
            if (hseq) hseq[(size_t)(r0 + rr) * (TSEQ * DIM) + (size_t)(t0 + t) * DIM + jj] = h;
        }
        __syncthreads();
    }
    if (tid < 128) {
        hstate[(r0 + rr) * DIM + jj] = hlast;
        cstate[(r0 + rr) * DIM + jj] = c;
    }
}

// ---------------- kernel 3: decoder (96 zero-state steps) ----------------
// R7 phase-3 structure (numerically proven), standalone at (512,2) budget 256.
#define DWFC 0
#define DP0  4096
#define DP1  4608
#define DH0  5120
#define DH1  5248
#define DDB  5376
#define DBS0 5504
#define DBS1 5760
#define DBFC 6016
#define DSMF 6080

extern "C" __global__ void __launch_bounds__(512, 2)
lstm_dec(const float* __restrict__ Wih0, const float* __restrict__ Wih1,
         const float* __restrict__ Wfc,
         const float* __restrict__ bih0, const float* __restrict__ bhh0,
         const float* __restrict__ bih1, const float* __restrict__ bhh1,
         const float* __restrict__ bfc,
         const float* __restrict__ h1last, float* __restrict__ out)
{
    __shared__ __align__(16) float sm[DSMF];
    const int tid = threadIdx.x;
    const int r0  = blockIdx.x * 2;
    const int rr  = (tid >> 6) & 1;
    const int jj  = tid & 63;
    const int dsub = tid >> 8;          // 0: Wih0 team, 1: Wih1 team
    const int g0d  = tid & 255;

    if (tid < 256) {
        sm[DBS0 + tid] = bih0[tid] + bhh0[tid];
        sm[DBS1 + tid] = bih1[tid] + bhh1[tid];
    }
    if (tid < 64) sm[DBFC + tid] = bfc[tid];
    for (int idx = tid; idx < DIM * DIM; idx += 512) {   // W_fc: (k4,c,j)
        const int j = idx >> 6, k = idx & 63;
        sm[DWFC + (k >> 2) * 256 + (k & 3) * 64 + j] = Wfc[idx];
    }
    if (tid < 128) sm[DDB + tid] = h1last[(r0 + rr) * DIM + jj];

    const float* Wsrc = dsub ? Wih1 : Wih0;
    float4 wd[16];
#pragma unroll
    for (int k4 = 0; k4 < 16; ++k4)
        wd[k4] = *reinterpret_cast<const float4*>(Wsrc + g0d * DIM + k4 * 4);
    __syncthreads();
    const float bfc_j = sm[DBFC + jj];

    for (int p = 0; p < PRED; ++p) {
        if (dsub == 0) {        // cell0: Wih0 . db (2 rows)
            float a0 = 0.f, a1 = 0.f;
#pragma unroll
            for (int k4 = 0; k4 < 16; ++k4) {
                fma4v(a0, *reinterpret_cast<const float4*>(sm + DDB + k4 * 4),      wd[k4]);
                fma4v(a1, *reinterpret_cast<const float4*>(sm + DDB + 64 + k4 * 4), wd[k4]);
            }
            sm[DP0 + g0d] = a0; sm[DP0 + 256 + g0d] = a1;
        }
        __syncthreads();
        if (tid < 128) {        // combine0: c = i*g
            const float* q = sm + DP0 + rr * 256;
            const float pi = sm[DBS0 + jj]        + q[jj];
            const float pg = sm[DBS0 + 128 + jj]  + q[128 + jj];
            const float po = sm[DBS0 + 192 + jj]  + q[192 + jj];
            const float ig = sigm(pi), gg = tanh_(pg), og = sigm(po);
            sm[DH0 + tid] = og * tanh_(ig * gg);
        }
        __syncthreads();
        if (dsub == 1) {        // cell1: Wih1 . h0
            float a0 = 0.f, a1 = 0.f;
#pragma unroll
            for (int k4 = 0; k4 < 16; ++k4) {
                fma4v(a0, *reinterpret_cast<const float4*>(sm + DH0 + k4 * 4),      wd[k4]);
                fma4v(a1, *reinterpret_cast<const float4*>(sm + DH0 + 64 + k4 * 4), wd[k4]);
            }
            sm[DP1 + g0d] = a0; sm[DP1 + 256 + g0d] = a1;
        }
        __syncthreads();
        if (tid < 128) {        // combine1 + FC (H1 row is wave-local)
            const float* q = sm + DP1 + rr * 256;
            const float pi = sm[DBS1 + jj]        + q[jj];
            const float pg = sm[DBS1 + 128 + jj]  + q[128 + jj];
            const float po = sm[DBS1 + 192 + jj]  + q[192 + jj];
            const float ig = sigm(pi), gg = tanh_(pg), og = sigm(po);
            sm[DH1 + tid] = og * tanh_(ig * gg);
            float acc = bfc_j;
            const float4* hp = reinterpret_cast<const float4*>(sm + DH1 + rr * 64);
#pragma unroll
            for (int k4 = 0; k4 < 16; ++k4) {
                const float4 hv = hp[k4];
                const float* wp = sm + DWFC + k4 * 256;
                acc = fmaf(hv.x, wp[jj],       acc);
                acc = fmaf(hv.y, wp[64 + jj],  acc);
                acc = fmaf(hv.z, wp[128 + jj], acc);
                acc = fmaf(hv.w, wp[192 + jj], acc);
            }
            out[(size_t)(r0 + rr) * PRED * DIM + p * DIM + jj] = acc;
            sm[DDB + tid] = acc;
        }
        __syncthreads();
    }
}

// ===================== FALLBACK: proven 512-thr baseline (1810 us) ==========
#define BP0O   0
#define BP1O   4096
#define BWFCO  8192
#define BH0O   12288
#define BH1O   12544
#define BDBO   12800
#define BBS0O  13056
#define BBS1O  13312
#define BBFCO  13568
#define BSMF   13632
#define BSMEM_BYTES (BSMF * 4)

extern "C" __global__ void __launch_bounds__(512, 2)
rnn_fused_base(const float* __restrict__ x,
          const float* __restrict__ Wih0, const float* __restrict__ Whh0,
          const float* __restrict__ bih0, const float* __restrict__ bhh0,
          const float* __restrict__ Wih1, const float* __restrict__ Whh1,
          const float* __restrict__ bih1, const float* __restrict__ bhh1,
          const float* __restrict__ Wfc,  const float* __restrict__ bfc,
          float* __restrict__ out)
{
    extern __shared__ float sm[];
    const int tid = threadIdx.x;
    const int bid = blockIdx.x;
    const int grp = tid >> 7;
    const int m   = grp & 1;
    const int kh  = grp >> 1;
    const int gp  = tid & 127;
    const int g0  = gp, g1 = gp + 128;
    const int rr  = (tid & 255) >> 6;
    const int jj  = tid & 63;

    if (tid < GATES) {
        sm[BBS0O + tid] = bih0[tid] + bhh0[tid];
        sm[BBS1O + tid] = bih1[tid] + bhh1[tid];
    }
    if (tid < DIM) sm[BBFCO + tid] = bfc[tid];
    if (tid < 256) { sm[BH0O + tid] = 0.0f; sm[BH1O + tid] = 0.0f; }
    for (int idx = tid; idx < DIM * DIM; idx += 512) {
        const int j = idx >> 6, k = idx & 63;
        sm[BWFCO + (k >> 2) * 256 + (k & 3) * 64 + j] = Wfc[idx];
    }

    const float* Wsrc0 = m ? Whh0 : Wih0;
    const float* Wsrc1 = m ? Whh1 : Wih1;
    float4 w0a[8], w0b[8], w1a[8], w1b[8];
#pragma unroll
    for (int k4 = 0; k4 < 8; ++k4) {
        w0a[k4] = *reinterpret_cast<const float4*>(Wsrc0 + g0 * DIM + kh * 32 + k4 * 4);
        w0b[k4] = *reinterpret_cast<const float4*>(Wsrc0 + g1 * DIM + kh * 32 + k4 * 4);
        w1a[k4] = *reinterpret_cast<const float4*>(Wsrc1 + g0 * DIM + kh * 32 + k4 * 4);
        w1b[k4] = *reinterpret_cast<const float4*>(Wsrc1 + g1 * DIM + kh * 32 + k4 * 4);
    }
    __syncthreads();

    const int row0 = bid * 4;
    const float* xr0 = x + (size_t)(row0 + 0) * TSEQ * DIM + kh * 32;
    const float* xr1 = x + (size_t)(row0 + 1) * TSEQ * DIM + kh * 32;
    const float* xr2 = x + (size_t)(row0 + 2) * TSEQ * DIM + kh * 32;
    const float* xr3 = x + (size_t)(row0 + 3) * TSEQ * DIM + kh * 32;

    const int pb = grp * 1024;
    float c_state = 0.0f;

    for (int s = 0; s < TSEQ; ++s) {
        if (s != 0 && tid >= 256) {
            float pi = sm[BBS1O + jj],       pf = sm[BBS1O + 64 + jj];
            float pg = sm[BBS1O + 128 + jj], po = sm[BBS1O + 192 + jj];
#pragma unroll
            for (int cp = 0; cp < 4; ++cp) {
                const float* p = sm + BP1O + cp * 1024 + rr * 256;
                pi += p[jj]; pf += p[64 + jj]; pg += p[128 + jj]; po += p[192 + jj];
            }
            const float ig = sigm(pi), fg = sigm(pf), gg = tanh_(pg), og = sigm(po);
            c_state = fmaf(fg, c_state, ig * gg);
            sm[BH1O + (tid & 255)] = og * tanh_(c_state);
        }
        {
            float acc[8];
#pragma unroll
            for (int i = 0; i < 8; ++i) acc[i] = 0.0f;
            if (m == 0) {
                const int so = s * DIM;
#pragma unroll
                for (int k4 = 0; k4 < 8; ++k4) {
                    const float4 v0 = *reinterpret_cast<const float4*>(xr0 + so + k4 * 4);
                    const float4 v1 = *reinterpret_cast<const float4*>(xr1 + so + k4 * 4);
                    const float4 v2 = *reinterpret_cast<const float4*>(xr2 + so + k4 * 4);
                    const float4 v3 = *reinterpret_cast<const float4*>(xr3 + so + k4 * 4);
                    fma4v(acc[0], v0, w0a[k4]); fma4v(acc[1], v0, w0b[k4]);
                    fma4v(acc[2], v1, w0a[k4]); fma4v(acc[3], v1, w0b[k4]);
                    fma4v(acc[4], v2, w0a[k4]); fma4v(acc[5], v2, w0b[k4]);
                    fma4v(acc[6], v3, w0a[k4]); fma4v(acc[7], v3, w0b[k4]);
                }
            } else {
#pragma unroll
                for (int k4 = 0; k4 < 8; ++k4) {
                    const float4 v0 = *reinterpret_cast<const float4*>(sm + BH0O + 0 * 64 + kh * 32 + k4 * 4);
                    const float4 v1 = *reinterpret_cast<const float4*>(sm + BH0O + 1 * 64 + kh * 32 + k4 * 4);
                    const float4 v2 = *reinterpret_cast<const float4*>(sm + BH0O + 2 * 64 + kh * 32 + k4 * 4);
                    const float4 v3 = *reinterpret_cast<const float4*>(sm + BH0O + 3 * 64 + kh * 32 + k4 * 4);
                    fma4v(acc[0], v0, w0a[k4]); fma4v(acc[1], v0, w0b[k4]);
                    fma4v(acc[2], v1, w0a[k4]); fma4v(acc[3], v1, w0b[k4]);
                    fma4v(acc[4], v2, w0a[k4]); fma4v(acc[5], v2, w0b[k4]);
                    fma4v(acc[6], v3, w0a[k4]); fma4v(acc[7], v3, w0b[k4]);
                }
            }
            sm[BP0O + pb + 0 * 256 + g0] = acc[0]; sm[BP0O + pb + 0 * 256 + g1] = acc[1];
            sm[BP0O + pb + 1 * 256 + g0] = acc[2]; sm[BP0O + pb + 1 * 256 + g1] = acc[3];
            sm[BP0O + pb + 2 * 256 + g0] = acc[4]; sm[BP0O + pb + 2 * 256 + g1] = acc[5];
            sm[BP0O + pb + 3 * 256 + g0] = acc[6]; sm[BP0O + pb + 3 * 256 + g1] = acc[7];
        }
        __syncthreads();

        if (tid < 256) {
            float pi = sm[BBS0O + jj],       pf = sm[BBS0O + 64 + jj];
            float pg = sm[BBS0O + 128 + jj], po = sm[BBS0O + 192 + jj];
#pragma unroll
            for (int cp = 0; cp < 4; ++cp) {
                const float* p = sm + BP0O + cp * 1024 + rr * 256;
                pi += p[jj]; pf += p[64 + jj]; pg += p[128 + jj]; po += p[192 + jj];
            }
            const float ig = sigm(pi), fg = sigm(pf), gg = tanh_(pg), og = sigm(po);
            c_state = fmaf(fg, c_state, ig * gg);
            sm[BH0O + tid] = og * tanh_(c_state);
        }
        __syncthreads();

        {
            const int ib = m ? BH1O : BH0O;
            float acc[8];
#pragma unroll
            for (int i = 0; i < 8; ++i) acc[i] = 0.0f;
#pragma unroll
            for (int k4 = 0; k4 < 8; ++k4) {
                const float4 v0 = *reinterpret_cast<const float4*>(sm + ib + 0 * 64 + kh * 32 + k4 * 4);
                const float4 v1 = *reinterpret_cast<const float4*>(sm + ib + 1 * 64 + kh * 32 + k4 * 4);
                const float4 v2 = *reinterpret_cast<const float4*>(sm + ib + 2 * 64 + kh * 32 + k4 * 4);
                const float4 v3 = *reinterpret_cast<const float4*>(sm + ib + 3 * 64 + kh * 32 + k4 * 4);
                fma4v(acc[0], v0, w1a[k4]); fma4v(acc[1], v0, w1b[k4]);
                fma4v(acc[2], v1, w1a[k4]); fma4v(acc[3], v1, w1b[k4]);
                fma4v(acc[4], v2, w1a[k4]); fma4v(acc[5], v2, w1b[k4]);
                fma4v(acc[6], v3, w1a[k4]); fma4v(acc[7], v3, w1b[k4]);
            }
            sm[BP1O + pb + 0 * 256 + g0] = acc[0]; sm[BP1O + pb + 0 * 256 + g1] = acc[1];
            sm[BP1O + pb + 1 * 256 + g0] = acc[2]; sm[BP1O + pb + 1 * 256 + g1] = acc[3];
            sm[BP1O + pb + 2 * 256 + g0] = acc[4]; sm[BP1O + pb + 2 * 256 + g1] = acc[5];
            sm[BP1O + pb + 3 * 256 + g0] = acc[6]; sm[BP1O + pb + 3 * 256 + g1] = acc[7];
        }
        __syncthreads();
    }

    if (tid >= 256) {
        float pi = sm[BBS1O + jj],       pf = sm[BBS1O + 64 + jj];
        float pg = sm[BBS1O + 128 + jj], po = sm[BBS1O + 192 + jj];
#pragma unroll
        for (int cp = 0; cp < 4; ++cp) {
            const float* p = sm + BP1O + cp * 1024 + rr * 256;
            pi += p[jj]; pf += p[64 + jj]; pg += p[128 + jj]; po += p[192 + jj];
        }
        const float ig = sigm(pi), fg = sigm(pf), gg = tanh_(pg), og = sigm(po);
        c_state = fmaf(fg, c_state, ig * gg);
        sm[BDBO + (tid & 255)] = og * tanh_(c_state);
    }
    __syncthreads();

    const float bfc_j = sm[BBFCO + jj];

    for (int p = 0; p < PRED; ++p) {
        if (m == 0) {
            float acc[8];
#pragma unroll
            for (int i = 0; i < 8; ++i) acc[i] = 0.0f;
#pragma unroll
            for (int k4 = 0; k4 < 8; ++k4) {
                const float4 v0 = *reinterpret_cast<const float4*>(sm + BDBO + 0 * 64 + kh * 32 + k4 * 4);
                const float4 v1 = *reinterpret_cast<const float4*>(sm + BDBO + 1 * 64 + kh * 32 + k4 * 4);
                const float4 v2 = *reinterpret_cast<const float4*>(sm + BDBO + 2 * 64 + kh * 32 + k4 * 4);
                const float4 v3 = *reinterpret_cast<const float4*>(sm + BDBO + 3 * 64 + kh * 32 + k4 * 4);
                fma4v(acc[0], v0, w0a[k4]); fma4v(acc[1], v0, w0b[k4]);
                fma4v(acc[2], v1, w0a[k4]); fma4v(acc[3], v1, w0b[k4]);
                fma4v(acc[4], v2, w0a[k4]); fma4v(acc[5], v2, w0b[k4]);
                fma4v(acc[6], v3, w0a[k4]); fma4v(acc[7], v3, w0b[k4]);
            }
            sm[BP0O + pb + 0 * 256 + g0] = acc[0]; sm[BP0O + pb + 0 * 256 + g1] = acc[1];
            sm[BP0O + pb + 1 * 256 + g0] = acc[2]; sm[BP0O + pb + 1 * 256 + g1] = acc[3];
            sm[BP0O + pb + 2 * 256 + g0] = acc[4]; sm[BP0O + pb + 2 * 256 + g1] = acc[5];
            sm[BP0O + pb + 3 * 256 + g0] = acc[6]; sm[BP0O + pb + 3 * 256 + g1] = acc[7];
        }
        __syncthreads();
        if (tid < 256) {
            float pi = sm[BBS0O + jj], pg = sm[BBS0O + 128 + jj], po = sm[BBS0O + 192 + jj];
            {
                const float* pA = sm + BP0O + 0 * 1024 + rr * 256;
                const float* pB = sm + BP0O + 2 * 1024 + rr * 256;
                pi += pA[jj] + pB[jj];
                pg += pA[128 + jj] + pB[128 + jj];
                po += pA[192 + jj] + pB[192 + jj];
            }
            const float ig = sigm(pi), gg = tanh_(pg), og = sigm(po);
            sm[BH0O + tid] = og * tanh_(ig * gg);
        }
        __syncthreads();

        if (m == 0) {
            float acc[8];
#pragma unroll
            for (int i = 0; i < 8; ++i) acc[i] = 0.0f;
#pragma unroll
            for (int k4 = 0; k4 < 8; ++k4) {
                const float4 v0 = *reinterpret_cast<const float4*>(sm + BH0O + 0 * 64 + kh * 32 + k4 * 4);
                const float4 v1 = *reinterpret_cast<const float4*>(sm + BH0O + 1 * 64 + kh * 32 + k4 * 4);
                const float4 v2 = *reinterpret_cast<const float4*>(sm + BH0O + 2 * 64 + kh * 32 + k4 * 4);
                const float4 v3 = *reinterpret_cast<const float4*>(sm + BH0O + 3 * 64 + kh * 32 + k4 * 4);
                fma4v(acc[0], v0, w1a[k4]); fma4v(acc[1], v0, w1b[k4]);
                fma4v(acc[2], v1, w1a[k4]); fma4v(acc[3], v1, w1b[k4]);
                fma4v(acc[4], v2, w1a[k4]); fma4v(acc[5], v2, w1b[k4]);
                fma4v(acc[6], v3, w1a[k4]); fma4v(acc[7], v3, w1b[k4]);
            }
            sm[BP1O + pb + 0 * 256 + g0] = acc[0]; sm[BP1O + pb + 0 * 256 + g1] = acc[1];
            sm[BP1O + pb + 1 * 256 + g0] = acc[2]; sm[BP1O + pb + 1 * 256 + g1] = acc[3];
            sm[BP1O + pb + 2 * 256 + g0] = acc[4]; sm[BP1O + pb + 2 * 256 + g1] = acc[5];
            sm[BP1O + pb + 3 * 256 + g0] = acc[6]; sm[BP1O + pb + 3 * 256 + g1] = acc[7];
        }
        __syncthreads();
        if (tid >= 256) {
            float pi = sm[BBS1O + jj], pg = sm[BBS1O + 128 + jj], po = sm[BBS1O + 192 + jj];
            {
                const float* pA = sm + BP1O + 0 * 1024 + rr * 256;
                const float* pB = sm + BP1O + 2 * 1024 + rr * 256;
                pi += pA[jj] + pB[jj];
                pg += pA[128 + jj] + pB[128 + jj];
                po += pA[192 + jj] + pB[192 + jj];
            }
            const float ig = sigm(pi), gg = tanh_(pg), og = sigm(po);
            sm[BH1O + (tid & 255)] = og * tanh_(ig * gg);
        }
        __syncthreads();

        if (tid < 256) {
            float acc = bfc_j;
            const float4* hp = reinterpret_cast<const float4*>(sm + BH1O + rr * 64);
#pragma unroll
            for (int k4 = 0; k4 < 16; ++k4) {
                const float4 hv = hp[k4];
                const float* wp = sm + BWFCO + k4 * 256;
                acc = fmaf(hv.x, wp[jj],       acc);
                acc = fmaf(hv.y, wp[64 + jj],  acc);
                acc = fmaf(hv.z, wp[128 + jj], acc);
                acc = fmaf(hv.w, wp[192 + jj], acc);
            }
            out[(size_t)(row0 + rr) * PRED * DIM + p * DIM + jj] = acc;
            sm[BDBO + tid] = acc;
        }
        __syncthreads();
    }
}

extern "C" void kernel_launch(void* const* d_in, const int* in_sizes, int n_in,
                              void* d_out, int out_size, void* d_ws, size_t ws_size,
                              hipStream_t stream) {
    const float* x    = (const float*)d_in[0];
    const float* Wih0 = (const float*)d_in[1];
    const float* Whh0 = (const float*)d_in[2];
    const float* bih0 = (const float*)d_in[3];
    const float* bhh0 = (const float*)d_in[4];
    const float* Wih1 = (const float*)d_in[5];
    const float* Whh1 = (const float*)d_in[6];
    const float* bih1 = (const float*)d_in[7];
    const float* bhh1 = (const float*)d_in[8];
    const float* Wfc  = (const float*)d_in[9];
    const float* bfc  = (const float*)d_in[10];
    float* out = (float*)d_out;

    // ws layout (floats): 4 state vectors (h0,c0,h1,c1: 1024x64 each),
    // h0 sequence (1024x336x64), pre buffer (1024 x tc x 256)
    const size_t base_fl = 4 * (size_t)NB * DIM + (size_t)NB * TSEQ * DIM;  // 22282240
    int tc = 0;
    if (d_ws) {
        const int cands[3] = {336, 168, 112};
        for (int i = 0; i < 3; ++i) {
            const size_t need = (base_fl + (size_t)NB * cands[i] * GATES) * 4;
            if (ws_size >= need) { tc = cands[i]; break; }
        }
    }
    if (tc == 0) {
        hipLaunchKernelGGL(rnn_fused_base, dim3(NB / 4), dim3(512), BSMEM_BYTES, stream,
                           x, Wih0, Whh0, bih0, bhh0, Wih1, Whh1, bih1, bhh1, Wfc, bfc, out);
        return;
    }

    float* wsf   = (float*)d_ws;
    float* st0h  = wsf;
    float* st0c  = wsf + (size_t)NB * DIM;
    float* st1h  = wsf + 2 * (size_t)NB * DIM;
    float* st1c  = wsf + 3 * (size_t)NB * DIM;
    float* h0seq = wsf + 4 * (size_t)NB * DIM;
    float* pre   = wsf + base_fl;

    const int nch = TSEQ / tc;
    for (int i = 0; i < nch; ++i) {
        const int t0 = i * tc;
        hipLaunchKernelGGL(gemm_pre, dim3(NB), dim3(512), 0, stream,
                           x + (size_t)t0 * DIM, Wih0, bih0, bhh0, pre, tc);
        hipLaunchKernelGGL(lstm_recur, dim3(NB / 2), dim3(512), 0, stream,
                           pre, tc, t0, Whh0, h0seq, st0h, st0c, (int)(i == 0));
        hipLaunchKernelGGL(gemm_pre, dim3(NB), dim3(512), 0, stream,
                           h0seq + (size_t)t0 * DIM, Wih1, bih1, bhh1, pre, tc);
        hipLaunchKernelGGL(lstm_recur, dim3(NB / 2), dim3(512), 0, stream,
                           pre, tc, t0, Whh1, (float*)nullptr, st1h, st1c, (int)(i == 0));
    }
    hipLaunchKernelGGL(lstm_dec, dim3(NB / 2), dim3(512), 0, stream,
                       Wih0, Wih1, Wfc, bih0, bhh0, bih1, bhh1, bfc, st1h, out);
}